// Round 2
// baseline (2459.640 us; speedup 1.0000x reference)
//
#include <hip/hip_runtime.h>
#include <hip/hip_bf16.h>

#define BB 8
#define CC 256
#define KCH 128
#define NCLS 21
#define NN 16384          // 128*128
#define IH 64
#define IW 64
#define GEPS 1e-5f

// ---- workspace layout (float elements) ----
#define OFF_PROBS 0u                     // 8*21*16384 = 2752512
#define OFF_CTX   2752512u               // 8*256*21   = 43008
#define OFF_KMAT  2795520u               // 8*128*21   = 21504
#define OFF_VMAT  2817024u               // 21504
#define OFF_STATS 2838528u               // 4 stages * 8 b * 2 = 64
#define OFF_T1    2838592u               // 8*128*16384 = 16777216
#define OFF_T2    19615808u              // 16777216
#define OFF_ATT   OFF_T1                 // reuse (t1 dead after conv2)
#define OFF_T3    OFF_T2                 // reuse (t2 dead after attn); 33554432 floats
// total = 19615808 + 33554432 = 53170240 floats (~213 MB) — fit confirmed in R1 (no fault)

// ---- block reduction helpers (blockDim.x == 256) ----
__device__ __forceinline__ float blk_sum(float v, float* red) {
    #pragma unroll
    for (int o = 32; o > 0; o >>= 1) v += __shfl_down(v, o, 64);
    int lane = threadIdx.x & 63, w = threadIdx.x >> 6;
    __syncthreads();
    if (lane == 0) red[w] = v;
    __syncthreads();
    return red[0] + red[1] + red[2] + red[3];
}
__device__ __forceinline__ float blk_max(float v, float* red) {
    #pragma unroll
    for (int o = 32; o > 0; o >>= 1) v = fmaxf(v, __shfl_down(v, o, 64));
    int lane = threadIdx.x & 63, w = threadIdx.x >> 6;
    __syncthreads();
    if (lane == 0) red[w] = v;
    __syncthreads();
    return fmaxf(fmaxf(red[0], red[1]), fmaxf(red[2], red[3]));
}

// ---- K1: bilinear (align_corners) 64x64 -> 128x128 + spatial softmax ----
__global__ __launch_bounds__(256) void interp_softmax_kernel(
    const float* __restrict__ aux, float* __restrict__ probs)
{
    int bk = blockIdx.x;                 // b*21 + k
    const float* src = aux + (size_t)bk * (IH * IW);
    float* dst = probs + (size_t)bk * NN;
    int tid = threadIdx.x;
    __shared__ float red[4];
    const float scale = 63.0f / 127.0f;
    float lmax = -1e30f;
    for (int idx = tid; idx < NN; idx += 256) {
        int y = idx >> 7, x = idx & 127;
        float fy = y * scale, fx = x * scale;
        int y0 = (int)fy, x0 = (int)fx;
        float wy = fy - y0, wx = fx - x0;
        int y1 = min(y0 + 1, IH - 1), x1 = min(x0 + 1, IW - 1);
        float v00 = src[y0 * IW + x0];
        float v01 = src[y0 * IW + x1];
        float v10 = src[y1 * IW + x0];
        float v11 = src[y1 * IW + x1];
        float v = (v00 * (1.f - wx) + v01 * wx) * (1.f - wy)
                + (v10 * (1.f - wx) + v11 * wx) * wy;
        dst[idx] = v;
        lmax = fmaxf(lmax, v);
    }
    float gmax = blk_max(lmax, red);
    float lsum = 0.f;
    for (int idx = tid; idx < NN; idx += 256) {
        float e = __expf(dst[idx] - gmax);
        dst[idx] = e;
        lsum += e;
    }
    float gsum = blk_sum(lsum, red);
    float inv = 1.0f / gsum;
    for (int idx = tid; idx < NN; idx += 256) dst[idx] *= inv;
}

// ---- K2: ctx[b,c,k] = sum_n probs[b,k,n] * feats[b,c,n] ----
__global__ __launch_bounds__(256) void ctx_kernel(
    const float* __restrict__ feats, const float* __restrict__ probs,
    float* __restrict__ ctx)
{
    int c = blockIdx.x, b = blockIdx.y, tid = threadIdx.x;
    const float* f = feats + ((size_t)(b * CC + c)) * NN;
    const float* p = probs + (size_t)b * NCLS * NN;
    float acc[NCLS];
    #pragma unroll
    for (int k = 0; k < NCLS; k++) acc[k] = 0.f;
    for (int n = tid; n < NN; n += 256) {
        float fv = f[n];
        #pragma unroll
        for (int k = 0; k < NCLS; k++) acc[k] += fv * p[(size_t)k * NN + n];
    }
    __shared__ float red[4 * NCLS];
    int lane = tid & 63, w = tid >> 6;
    #pragma unroll
    for (int k = 0; k < NCLS; k++) {
        float v = acc[k];
        #pragma unroll
        for (int o = 32; o > 0; o >>= 1) v += __shfl_down(v, o, 64);
        if (lane == 0) red[w * NCLS + k] = v;
    }
    __syncthreads();
    if (tid < NCLS) {
        ctx[((size_t)(b * CC + c)) * NCLS + tid] =
            red[tid] + red[NCLS + tid] + red[2 * NCLS + tid] + red[3 * NCLS + tid];
    }
}

// ---- K3: k/v branches (per-batch block): conv -> GN -> relu chains on [*,21] ----
__device__ void kv_branch(const float* src, int Cs, const float* W,
                          const float* g, const float* bb, float* dst, float* red)
{
    int tid = threadIdx.x;
    float s = 0.f, s2 = 0.f;
    for (int idx = tid; idx < KCH * NCLS; idx += 256) {
        int o = idx / NCLS, k = idx - o * NCLS;
        const float* wr = W + (size_t)o * Cs;
        float acc = 0.f;
        for (int c = 0; c < Cs; c++) acc += wr[c] * src[c * NCLS + k];
        dst[idx] = acc;
        s += acc; s2 += acc * acc;
    }
    __syncthreads();
    s = blk_sum(s, red);
    s2 = blk_sum(s2, red);
    const float inv = 1.0f / (KCH * NCLS);
    float mean = s * inv;
    float var = s2 * inv - mean * mean;
    float rstd = rsqrtf(var + GEPS);
    for (int idx = tid; idx < KCH * NCLS; idx += 256) {
        int o = idx / NCLS;
        float v = (dst[idx] - mean) * rstd * g[o] + bb[o];
        dst[idx] = fmaxf(v, 0.f);
    }
    __syncthreads();
}

__global__ __launch_bounds__(256) void kv_kernel(
    const float* __restrict__ ctx,
    const float* fo_w1, const float* fo_g1, const float* fo_b1,
    const float* fo_w2, const float* fo_g2, const float* fo_b2,
    const float* fd_w, const float* fd_g, const float* fd_b,
    float* __restrict__ kmat, float* __restrict__ vmat)
{
    __shared__ float sctx[CC * NCLS];
    __shared__ float h1[KCH * NCLS];
    __shared__ float h2[KCH * NCLS];
    __shared__ float red[4];
    int b = blockIdx.x, tid = threadIdx.x;
    for (int i = tid; i < CC * NCLS; i += 256) sctx[i] = ctx[(size_t)b * CC * NCLS + i];
    __syncthreads();
    // k = relu(gn(fo_w2 @ relu(gn(fo_w1 @ ctx))))
    kv_branch(sctx, CC, fo_w1, fo_g1, fo_b1, h1, red);
    kv_branch(h1, KCH, fo_w2, fo_g2, fo_b2, h2, red);
    for (int i = tid; i < KCH * NCLS; i += 256) kmat[(size_t)b * KCH * NCLS + i] = h2[i];
    // v = relu(gn(fd_w @ ctx))
    kv_branch(sctx, CC, fd_w, fd_g, fd_b, h1, red);
    for (int i = tid; i < KCH * NCLS; i += 256) vmat[(size_t)b * KCH * NCLS + i] = h1[i];
}

// ---- generic 1x1-conv GEMM: out[b,o,n] = sum_c W[o,c]*X[b,c,n] ----
// in1 channels [0,K1): optional GN+relu on the fly; in2 channels [K1,K1+K2): raw.
// Accumulates per-b sum/sumsq of raw outputs into ostat (atomicAdd).
__global__ __launch_bounds__(256) void gemm_cn(
    const float* __restrict__ in1, const float* __restrict__ in2,
    const float* __restrict__ W, float* __restrict__ outv,
    int K1, int K2,
    const float* __restrict__ nstat, float ninv,
    const float* __restrict__ ngam, const float* __restrict__ nbet,
    float* __restrict__ ostat)
{
    __shared__ float Ws[64][17];
    __shared__ float Xs[16][64];
    __shared__ float red[8];
    int b = blockIdx.z;
    int o0 = blockIdx.y * 64, n0 = blockIdx.x * 64;
    int Ktot = K1 + K2;
    int tid = threadIdx.x;
    int tx = tid & 15, ty = tid >> 4;

    float mean = 0.f, rstd = 0.f;
    if (nstat) {
        float s = nstat[2 * b], s2 = nstat[2 * b + 1];
        mean = s * ninv;
        float var = s2 * ninv - mean * mean;
        rstd = rsqrtf(var + GEPS);
    }

    float acc[4][4] = {};
    for (int c0 = 0; c0 < Ktot; c0 += 16) {
        #pragma unroll
        for (int l = 0; l < 4; l++) {
            int idx = tid + l * 256;
            int k = idx & 15, o = idx >> 4;
            Ws[o][k] = W[(size_t)(o0 + o) * Ktot + c0 + k];
        }
        #pragma unroll
        for (int l = 0; l < 4; l++) {
            int idx = tid + l * 256;
            int n = idx & 63, k = idx >> 6;
            int c = c0 + k;
            float v;
            if (c < K1) {
                v = in1[((size_t)(b * K1 + c)) * NN + n0 + n];
                if (nstat) {
                    v = (v - mean) * rstd * ngam[c] + nbet[c];
                    v = fmaxf(v, 0.f);
                }
            } else {
                v = in2[((size_t)(b * K2 + (c - K1))) * NN + n0 + n];
            }
            Xs[k][n] = v;
        }
        __syncthreads();
        #pragma unroll
        for (int kk = 0; kk < 16; kk++) {
            float a[4], x[4];
            #pragma unroll
            for (int i = 0; i < 4; i++) a[i] = Ws[ty + 16 * i][kk];
            #pragma unroll
            for (int j = 0; j < 4; j++) x[j] = Xs[kk][tx + 16 * j];
            #pragma unroll
            for (int i = 0; i < 4; i++)
                #pragma unroll
                for (int j = 0; j < 4; j++) acc[i][j] += a[i] * x[j];
        }
        __syncthreads();
    }

    int O = gridDim.y * 64;
    float s = 0.f, s2 = 0.f;
    #pragma unroll
    for (int i = 0; i < 4; i++) {
        int o = o0 + ty + 16 * i;
        #pragma unroll
        for (int j = 0; j < 4; j++) {
            int n = n0 + tx + 16 * j;
            float v = acc[i][j];
            outv[((size_t)(b * O + o)) * NN + n] = v;
            s += v; s2 += v * v;
        }
    }
    if (ostat) {
        #pragma unroll
        for (int o = 32; o > 0; o >>= 1) {
            s += __shfl_down(s, o, 64);
            s2 += __shfl_down(s2, o, 64);
        }
        int lane = tid & 63, w = tid >> 6;
        if (lane == 0) { red[w] = s; red[4 + w] = s2; }
        __syncthreads();
        if (tid == 0) {
            atomicAdd(&ostat[2 * b], red[0] + red[1] + red[2] + red[3]);
            atomicAdd(&ostat[2 * b + 1], red[4] + red[5] + red[6] + red[7]);
        }
    }
}

// ---- K7: attention. q = relu(gn(t2)); sim=softmax(q^T k / sqrt(kc)); att = v sim^T ----
__global__ __launch_bounds__(256) void attn_kernel(
    const float* __restrict__ t2, const float* __restrict__ kmat,
    const float* __restrict__ vmat, const float* __restrict__ stat,
    const float* __restrict__ g2, const float* __restrict__ b2,
    float* __restrict__ att)
{
    __shared__ float sk[KCH * NCLS];
    __shared__ float sv[KCH * NCLS];
    int b = blockIdx.y;
    int n = blockIdx.x * 256 + threadIdx.x;
    for (int i = threadIdx.x; i < KCH * NCLS; i += 256) {
        sk[i] = kmat[(size_t)b * KCH * NCLS + i];
        sv[i] = vmat[(size_t)b * KCH * NCLS + i];
    }
    __syncthreads();
    const float cinv = 1.0f / (128.f * 16384.f);
    float s = stat[2 * b], s2_ = stat[2 * b + 1];
    float mean = s * cinv;
    float var = s2_ * cinv - mean * mean;
    float rstd = rsqrtf(var + GEPS);

    float sim[NCLS] = {};
    const float* q = t2 + (size_t)b * KCH * NN + n;
    for (int c = 0; c < KCH; c++) {
        float qv = q[(size_t)c * NN];
        qv = fmaxf((qv - mean) * rstd * g2[c] + b2[c], 0.f);
        #pragma unroll
        for (int k = 0; k < NCLS; k++) sim[k] += qv * sk[c * NCLS + k];
    }
    const float scale = 0.08838834764831845f;  // 128^-0.5
    float m = -1e30f;
    #pragma unroll
    for (int k = 0; k < NCLS; k++) { sim[k] *= scale; m = fmaxf(m, sim[k]); }
    float ssum = 0.f;
    #pragma unroll
    for (int k = 0; k < NCLS; k++) { sim[k] = __expf(sim[k] - m); ssum += sim[k]; }
    float inv = 1.0f / ssum;
    #pragma unroll
    for (int k = 0; k < NCLS; k++) sim[k] *= inv;

    float* o = att + (size_t)b * KCH * NN + n;
    for (int c = 0; c < KCH; c++) {
        float acc = 0.f;
        #pragma unroll
        for (int k = 0; k < NCLS; k++) acc += sim[k] * sv[c * NCLS + k];
        o[(size_t)c * NN] = acc;
    }
}

// ---- K10: in-place final GN + relu on fp32 d_out ----
__global__ __launch_bounds__(256) void final_norm_kernel(
    float4* __restrict__ out, const float* __restrict__ stat,
    const float* __restrict__ g, const float* __restrict__ bb)
{
    size_t i = (size_t)blockIdx.x * 256 + threadIdx.x;
    size_t base = i * 4;
    int b = (int)(base >> 22);          // 256*16384 per batch
    int c = (int)((base >> 14) & 255);
    const float cinv = 1.0f / (256.f * 16384.f);
    float s = stat[2 * b], s2 = stat[2 * b + 1];
    float mean = s * cinv;
    float var = s2 * cinv - mean * mean;
    float rstd = rsqrtf(var + GEPS);
    float gg = g[c];
    float bv = bb[c];
    float4 u = out[i];
    u.x = fmaxf((u.x - mean) * rstd * gg + bv, 0.f);
    u.y = fmaxf((u.y - mean) * rstd * gg + bv, 0.f);
    u.z = fmaxf((u.z - mean) * rstd * gg + bv, 0.f);
    u.w = fmaxf((u.w - mean) * rstd * gg + bv, 0.f);
    out[i] = u;
}

extern "C" void kernel_launch(void* const* d_in, const int* in_sizes, int n_in,
                              void* d_out, int out_size, void* d_ws, size_t ws_size,
                              hipStream_t stream) {
    const float* feats   = (const float*)d_in[0];
    const float* out_aux = (const float*)d_in[1];
    const float* fp_w1 = (const float*)d_in[2];
    const float* fp_g1 = (const float*)d_in[3];
    const float* fp_b1 = (const float*)d_in[4];
    const float* fp_w2 = (const float*)d_in[5];
    const float* fp_g2 = (const float*)d_in[6];
    const float* fp_b2 = (const float*)d_in[7];
    const float* fo_w1 = (const float*)d_in[8];
    const float* fo_g1 = (const float*)d_in[9];
    const float* fo_b1 = (const float*)d_in[10];
    const float* fo_w2 = (const float*)d_in[11];
    const float* fo_g2 = (const float*)d_in[12];
    const float* fo_b2 = (const float*)d_in[13];
    const float* fd_w  = (const float*)d_in[14];
    const float* fd_g  = (const float*)d_in[15];
    const float* fd_b  = (const float*)d_in[16];
    const float* fu_w  = (const float*)d_in[17];
    const float* fu_g  = (const float*)d_in[18];
    const float* fu_b  = (const float*)d_in[19];
    const float* cb_w  = (const float*)d_in[20];
    const float* cb_g  = (const float*)d_in[21];
    const float* cb_b  = (const float*)d_in[22];

    float* ws = (float*)d_ws;
    float* probs = ws + OFF_PROBS;
    float* ctx   = ws + OFF_CTX;
    float* kmat  = ws + OFF_KMAT;
    float* vmat  = ws + OFF_VMAT;
    float* stats = ws + OFF_STATS;   // [4 stages][8 b][2]
    float* t1    = ws + OFF_T1;
    float* t2    = ws + OFF_T2;
    float* att   = ws + OFF_ATT;     // reuses t1
    float* t3    = ws + OFF_T3;      // reuses t2 (and beyond)
    float* st0 = stats, *st1 = stats + 16, *st2 = stats + 32, *st3 = stats + 48;

    hipMemsetAsync(stats, 0, 64 * sizeof(float), stream);

    // probs + softmax
    interp_softmax_kernel<<<BB * NCLS, 256, 0, stream>>>(out_aux, probs);
    // ctx gather
    ctx_kernel<<<dim3(CC, BB), 256, 0, stream>>>(feats, probs, ctx);
    // k/v
    kv_kernel<<<BB, 256, 0, stream>>>(ctx, fo_w1, fo_g1, fo_b1, fo_w2, fo_g2, fo_b2,
                                      fd_w, fd_g, fd_b, kmat, vmat);
    // t1 = fp_w1 @ feats  (+stats0)
    gemm_cn<<<dim3(NN / 64, KCH / 64, BB), 256, 0, stream>>>(
        feats, nullptr, fp_w1, t1, CC, 0, nullptr, 0.f, nullptr, nullptr, st0);
    // t2 = fp_w2 @ relu(gn(t1))  (+stats1)
    gemm_cn<<<dim3(NN / 64, KCH / 64, BB), 256, 0, stream>>>(
        t1, nullptr, fp_w2, t2, KCH, 0, st0, 1.f / (KCH * (float)NN), fp_g1, fp_b1, st1);
    // attention: q = relu(gn(t2)); att = v @ softmax(q^T k / sqrt(kc))
    attn_kernel<<<dim3(NN / 256, BB), 256, 0, stream>>>(t2, kmat, vmat, st1, fp_g2, fp_b2, att);
    // t3 = fu_w @ att  (+stats2)
    gemm_cn<<<dim3(NN / 64, CC / 64, BB), 256, 0, stream>>>(
        att, nullptr, fu_w, t3, KCH, 0, nullptr, 0.f, nullptr, nullptr, st2);
    // d_out(raw) = cb_w @ concat(relu(gn(t3)), feats)  (+stats3)
    gemm_cn<<<dim3(NN / 64, CC / 64, BB), 256, 0, stream>>>(
        t3, feats, cb_w, (float*)d_out, CC, CC, st2, 1.f / (CC * (float)NN), fu_g, fu_b, st3);
    // final in-place gn + relu
    final_norm_kernel<<<(BB * CC * NN) / (4 * 256), 256, 0, stream>>>(
        (float4*)d_out, st3, cb_g, cb_b);
}

// Round 3
// 915.620 us; speedup vs baseline: 2.6863x; 2.6863x over previous
//
#include <hip/hip_runtime.h>
#include <hip/hip_bf16.h>

#define BB 8
#define CC 256
#define KCH 128
#define NCLS 21
#define NN 16384          // 128*128
#define IH 64
#define IW 64
#define GEPS 1e-5f

typedef unsigned short u16;
typedef short v8s __attribute__((ext_vector_type(8)));
typedef u16 v8us __attribute__((ext_vector_type(8)));
typedef float v4f __attribute__((ext_vector_type(4)));

// ---- workspace layout (float elements) ----
// smalls
#define OFF_STATS   0u          // 64
#define OFF_CTX     64u         // 43008
#define OFF_KMAT    43072u      // 21504
#define OFF_VMAT    64576u      // 21504
#define OFF_WB1     86080u      // 32768 bf16 -> 16384 f
#define OFF_WB2     102464u     // 16384 bf16 -> 8192 f
#define OFF_WB3     110656u     // 32768 bf16 -> 16384 f
#define OFF_WB4     127040u     // 131072 bf16 -> 65536 f -> end 192576
#define OFF_FEATSB  196608u     // 33554432 bf16 -> 16777216 f -> end 16973824
#define OFF_POOL    16973824u
// pool usage (all stream-ordered, read-buf != write-buf per kernel):
//   probs  fp32 2752512  @ POOL+0         (live K1-K2, before t1 exists)
//   t1     fp32 16777216 @ POOL+0
//   x2     bf16 ->8388608f @ POOL+16777216
//   t2     fp32 16777216 @ POOL+0         (t1 dead)
//   att    bf16 ->8388608f @ POOL+25165824
//   t3     bf16 ->16777216f(33.5M elems->16.77Mf? no: 33554432 bf16 = 16777216f) @ POOL+0
//   x4a    bf16 ->16777216f @ POOL+16777216
//   t4     bf16 ->16777216f @ POOL+0
// peak end = POOL + 33554432 = 50528256 floats < 53170240 (proven fit in R1)

__device__ __forceinline__ float bfu2f(u16 u) {
    unsigned int x = ((unsigned int)u) << 16;
    return __uint_as_float(x);
}
__device__ __forceinline__ u16 f2bfu(float f) {
    __hip_bfloat16 h = __float2bfloat16(f);
    return *reinterpret_cast<u16*>(&h);
}

// ---- block reduction helpers (blockDim.x == 256) ----
__device__ __forceinline__ float blk_sum(float v, float* red) {
    #pragma unroll
    for (int o = 32; o > 0; o >>= 1) v += __shfl_down(v, o, 64);
    int lane = threadIdx.x & 63, w = threadIdx.x >> 6;
    __syncthreads();
    if (lane == 0) red[w] = v;
    __syncthreads();
    return red[0] + red[1] + red[2] + red[3];
}
__device__ __forceinline__ float blk_max(float v, float* red) {
    #pragma unroll
    for (int o = 32; o > 0; o >>= 1) v = fmaxf(v, __shfl_down(v, o, 64));
    int lane = threadIdx.x & 63, w = threadIdx.x >> 6;
    __syncthreads();
    if (lane == 0) red[w] = v;
    __syncthreads();
    return fmaxf(fmaxf(red[0], red[1]), fmaxf(red[2], red[3]));
}

// ---- weights fp32 -> bf16 ----
__global__ __launch_bounds__(256) void conv_weights(
    const float* __restrict__ w1, const float* __restrict__ w2,
    const float* __restrict__ w3, const float* __restrict__ w4,
    u16* __restrict__ o1, u16* __restrict__ o2,
    u16* __restrict__ o3, u16* __restrict__ o4)
{
    int i = blockIdx.x * 256 + threadIdx.x;
    if (i < 32768) o1[i] = f2bfu(w1[i]);
    else if (i < 49152) o2[i - 32768] = f2bfu(w2[i - 32768]);
    else if (i < 81920) o3[i - 49152] = f2bfu(w3[i - 49152]);
    else if (i < 212992) o4[i - 81920] = f2bfu(w4[i - 81920]);
}

// ---- feats NCHW fp32 -> NHWC bf16 (tiled transpose) ----
__global__ __launch_bounds__(256) void feats_to_nhwc(
    const float* __restrict__ feats, u16* __restrict__ outp)
{
    __shared__ float tile[64][65];
    int b = blockIdx.z, c0 = blockIdx.y * 64, n0 = blockIdx.x * 64;
    int tid = threadIdx.x, tx = tid & 63, ty = tid >> 6;
    #pragma unroll
    for (int r = 0; r < 16; r++) {
        int c = ty * 16 + r;
        tile[c][tx] = feats[((size_t)(b * CC + c0 + c)) * NN + n0 + tx];
    }
    __syncthreads();
    #pragma unroll
    for (int r = 0; r < 16; r++) {
        int nl = ty * 16 + r;
        outp[((size_t)b * NN + n0 + nl) * CC + c0 + tx] = f2bfu(tile[tx][nl]);
    }
}

// ---- K1: bilinear (align_corners) 64x64 -> 128x128 + spatial softmax ----
__global__ __launch_bounds__(256) void interp_softmax_kernel(
    const float* __restrict__ aux, float* __restrict__ probs)
{
    int bk = blockIdx.x;                 // b*21 + k
    const float* src = aux + (size_t)bk * (IH * IW);
    float* dst = probs + (size_t)bk * NN;
    int tid = threadIdx.x;
    __shared__ float red[4];
    const float scale = 63.0f / 127.0f;
    float lmax = -1e30f;
    for (int idx = tid; idx < NN; idx += 256) {
        int y = idx >> 7, x = idx & 127;
        float fy = y * scale, fx = x * scale;
        int y0 = (int)fy, x0 = (int)fx;
        float wy = fy - y0, wx = fx - x0;
        int y1 = min(y0 + 1, IH - 1), x1 = min(x0 + 1, IW - 1);
        float v00 = src[y0 * IW + x0];
        float v01 = src[y0 * IW + x1];
        float v10 = src[y1 * IW + x0];
        float v11 = src[y1 * IW + x1];
        float v = (v00 * (1.f - wx) + v01 * wx) * (1.f - wy)
                + (v10 * (1.f - wx) + v11 * wx) * wy;
        dst[idx] = v;
        lmax = fmaxf(lmax, v);
    }
    float gmax = blk_max(lmax, red);
    float lsum = 0.f;
    for (int idx = tid; idx < NN; idx += 256) {
        float e = __expf(dst[idx] - gmax);
        dst[idx] = e;
        lsum += e;
    }
    float gsum = blk_sum(lsum, red);
    float inv = 1.0f / gsum;
    for (int idx = tid; idx < NN; idx += 256) dst[idx] *= inv;
}

// ---- K2: ctx[b,c,k] = sum_n probs[b,k,n] * feats[b,c,n] (NCHW feats) ----
__global__ __launch_bounds__(256) void ctx_kernel(
    const float* __restrict__ feats, const float* __restrict__ probs,
    float* __restrict__ ctx)
{
    int c = blockIdx.x, b = blockIdx.y, tid = threadIdx.x;
    const float* f = feats + ((size_t)(b * CC + c)) * NN;
    const float* p = probs + (size_t)b * NCLS * NN;
    float acc[NCLS];
    #pragma unroll
    for (int k = 0; k < NCLS; k++) acc[k] = 0.f;
    for (int n = tid; n < NN; n += 256) {
        float fv = f[n];
        #pragma unroll
        for (int k = 0; k < NCLS; k++) acc[k] += fv * p[(size_t)k * NN + n];
    }
    __shared__ float red[4 * NCLS];
    int lane = tid & 63, w = tid >> 6;
    #pragma unroll
    for (int k = 0; k < NCLS; k++) {
        float v = acc[k];
        #pragma unroll
        for (int o = 32; o > 0; o >>= 1) v += __shfl_down(v, o, 64);
        if (lane == 0) red[w * NCLS + k] = v;
    }
    __syncthreads();
    if (tid < NCLS) {
        ctx[((size_t)(b * CC + c)) * NCLS + tid] =
            red[tid] + red[NCLS + tid] + red[2 * NCLS + tid] + red[3 * NCLS + tid];
    }
}

// ---- K3: k/v branches ----
__device__ void kv_branch(const float* src, int Cs, const float* W,
                          const float* g, const float* bb, float* dst, float* red)
{
    int tid = threadIdx.x;
    float s = 0.f, s2 = 0.f;
    for (int idx = tid; idx < KCH * NCLS; idx += 256) {
        int o = idx / NCLS, k = idx - o * NCLS;
        const float* wr = W + (size_t)o * Cs;
        float acc = 0.f;
        for (int c = 0; c < Cs; c++) acc += wr[c] * src[c * NCLS + k];
        dst[idx] = acc;
        s += acc; s2 += acc * acc;
    }
    __syncthreads();
    s = blk_sum(s, red);
    s2 = blk_sum(s2, red);
    const float inv = 1.0f / (KCH * NCLS);
    float mean = s * inv;
    float var = s2 * inv - mean * mean;
    float rstd = rsqrtf(var + GEPS);
    for (int idx = tid; idx < KCH * NCLS; idx += 256) {
        int o = idx / NCLS;
        float v = (dst[idx] - mean) * rstd * g[o] + bb[o];
        dst[idx] = fmaxf(v, 0.f);
    }
    __syncthreads();
}

__global__ __launch_bounds__(256) void kv_kernel(
    const float* __restrict__ ctx,
    const float* fo_w1, const float* fo_g1, const float* fo_b1,
    const float* fo_w2, const float* fo_g2, const float* fo_b2,
    const float* fd_w, const float* fd_g, const float* fd_b,
    float* __restrict__ kmat, float* __restrict__ vmat)
{
    __shared__ float sctx[CC * NCLS];
    __shared__ float h1[KCH * NCLS];
    __shared__ float h2[KCH * NCLS];
    __shared__ float red[4];
    int b = blockIdx.x, tid = threadIdx.x;
    for (int i = tid; i < CC * NCLS; i += 256) sctx[i] = ctx[(size_t)b * CC * NCLS + i];
    __syncthreads();
    kv_branch(sctx, CC, fo_w1, fo_g1, fo_b1, h1, red);
    kv_branch(h1, KCH, fo_w2, fo_g2, fo_b2, h2, red);
    for (int i = tid; i < KCH * NCLS; i += 256) kmat[(size_t)b * KCH * NCLS + i] = h2[i];
    kv_branch(sctx, CC, fd_w, fd_g, fd_b, h1, red);
    for (int i = tid; i < KCH * NCLS; i += 256) vmat[(size_t)b * KCH * NCLS + i] = h1[i];
}

// ---- MFMA GEMM: out[b][n][o] = sum_c X[b][n][c] * W[o][c]  (all bf16 in) ----
// X split: c in [0,K1) from xa, [K1,KTOT) from xb. 128x128 tile, BK=32, 4 waves.
template<int KTOT, int K1, bool OUT_BF16>
__global__ __launch_bounds__(256) void mfma_gemm(
    const u16* __restrict__ xa, const u16* __restrict__ xb,
    const u16* __restrict__ wmat, void* __restrict__ outv,
    int Odim, float* __restrict__ ostat)
{
    __shared__ u16 lA[128 * 32];
    __shared__ u16 lB[128 * 32];
    __shared__ float red[8];
    const int b = blockIdx.z;
    const int n0 = blockIdx.x * 128;
    const int o0 = blockIdx.y * 128;
    const int tid = threadIdx.x;
    const int wave = tid >> 6, lane = tid & 63;
    const int quad = lane >> 4, l15 = lane & 15;
    const int wm = (wave & 1) * 64, wn = (wave >> 1) * 64;
    const int srow = lane >> 2;         // 0..15
    const int skc = (lane & 3) * 8;     // 0/8/16/24
    const size_t xbase = (size_t)b * NN + n0;

    v4f acc[4][4] = {};

    for (int c0 = 0; c0 < KTOT; c0 += 32) {
        // stage A (X rows n0..n0+128) — lane*16B contiguous LDS, conflict-free
        #pragma unroll
        for (int t = 0; t < 2; t++) {
            int inst = wave * 2 + t;
            int row = inst * 16 + srow;
            int cc = c0 + skc;
            const u16* src;
            if (K1 == KTOT || cc < K1)
                src = xa + (xbase + row) * K1 + cc;
            else
                src = xb + (xbase + row) * (KTOT - K1) + (cc - K1);
            v8s v = *(const v8s*)src;
            *(v8s*)&lA[inst * 512 + lane * 8] = v;
        }
        // stage B (W rows o0..o0+128)
        #pragma unroll
        for (int t = 0; t < 2; t++) {
            int inst = wave * 2 + t;
            int row = inst * 16 + srow;
            v8s v = *(const v8s*)(wmat + (size_t)(o0 + row) * KTOT + c0 + skc);
            *(v8s*)&lB[inst * 512 + lane * 8] = v;
        }
        __syncthreads();
        v8s af[4], bfr[4];
        #pragma unroll
        for (int i = 0; i < 4; i++)
            af[i] = *(const v8s*)&lA[(wm + i * 16 + l15) * 32 + quad * 8];
        #pragma unroll
        for (int j = 0; j < 4; j++)
            bfr[j] = *(const v8s*)&lB[(wn + j * 16 + l15) * 32 + quad * 8];
        #pragma unroll
        for (int i = 0; i < 4; i++)
            #pragma unroll
            for (int j = 0; j < 4; j++)
                acc[i][j] = __builtin_amdgcn_mfma_f32_16x16x32_bf16(
                    af[i], bfr[j], acc[i][j], 0, 0, 0);
        __syncthreads();
    }

    // epilogue: store + per-b sum/sumsq
    float s = 0.f, s2 = 0.f;
    #pragma unroll
    for (int i = 0; i < 4; i++) {
        #pragma unroll
        for (int j = 0; j < 4; j++) {
            #pragma unroll
            for (int r = 0; r < 4; r++) {
                float v = acc[i][j][r];
                int n = n0 + wm + i * 16 + quad * 4 + r;
                int o = o0 + wn + j * 16 + l15;
                size_t addr = ((size_t)b * NN + n) * (size_t)Odim + o;
                if (OUT_BF16) ((u16*)outv)[addr] = f2bfu(v);
                else ((float*)outv)[addr] = v;
                s += v; s2 += v * v;
            }
        }
    }
    #pragma unroll
    for (int o = 32; o > 0; o >>= 1) {
        s += __shfl_down(s, o, 64);
        s2 += __shfl_down(s2, o, 64);
    }
    if (lane == 0) { red[wave] = s; red[4 + wave] = s2; }
    __syncthreads();
    if (tid == 0) {
        atomicAdd(&ostat[2 * b], red[0] + red[1] + red[2] + red[3]);
        atomicAdd(&ostat[2 * b + 1], red[4] + red[5] + red[6] + red[7]);
    }
}

// ---- GN+relu+bf16 convert, NHWC elementwise, 8 elems/thread ----
template<bool IN_BF16>
__global__ __launch_bounds__(256) void norm_convert(
    const void* __restrict__ inv, u16* __restrict__ outp,
    const float* __restrict__ stat, float ninv,
    const float* __restrict__ gam, const float* __restrict__ bet,
    int cmask, int bshift8)
{
    size_t f8 = (size_t)blockIdx.x * 256 + threadIdx.x;
    int b = (int)(f8 >> bshift8);
    int c = (int)((f8 * 8) & (size_t)cmask);
    float sm = stat[2 * b], sq = stat[2 * b + 1];
    float mean = sm * ninv;
    float var = sq * ninv - mean * mean;
    float rstd = rsqrtf(var + GEPS);
    float x[8];
    if (IN_BF16) {
        v8us v = ((const v8us*)inv)[f8];
        #pragma unroll
        for (int e = 0; e < 8; e++) x[e] = bfu2f(v[e]);
    } else {
        const float4* p = (const float4*)inv + f8 * 2;
        float4 a = p[0], d = p[1];
        x[0] = a.x; x[1] = a.y; x[2] = a.z; x[3] = a.w;
        x[4] = d.x; x[5] = d.y; x[6] = d.z; x[7] = d.w;
    }
    v8us o;
    #pragma unroll
    for (int e = 0; e < 8; e++) {
        float v = (x[e] - mean) * rstd * gam[c + e] + bet[c + e];
        o[e] = f2bfu(fmaxf(v, 0.f));
    }
    ((v8us*)outp)[f8] = o;
}

// ---- attention: q=relu(gn(t2)) [NHWC fp32]; att[b][n][c] bf16 NHWC ----
__global__ __launch_bounds__(256) void attn_kernel(
    const float* __restrict__ t2, const float* __restrict__ kmat,
    const float* __restrict__ vmat, const float* __restrict__ stat,
    const float* __restrict__ g2, const float* __restrict__ b2,
    u16* __restrict__ att)
{
    __shared__ float sk[KCH * NCLS];
    __shared__ float sv[KCH * NCLS];
    __shared__ float sgam[KCH], sbet[KCH];
    __shared__ float sims[256][NCLS + 1];
    int b = blockIdx.y;
    int n0 = blockIdx.x * 256;
    int tid = threadIdx.x;
    for (int i = tid; i < KCH * NCLS; i += 256) {
        sk[i] = kmat[(size_t)b * KCH * NCLS + i];
        sv[i] = vmat[(size_t)b * KCH * NCLS + i];
    }
    if (tid < KCH) { sgam[tid] = g2[tid]; sbet[tid] = b2[tid]; }
    __syncthreads();
    const float cinv = 1.0f / (128.f * 16384.f);
    float sm = stat[2 * b], sq = stat[2 * b + 1];
    float mean = sm * cinv;
    float var = sq * cinv - mean * mean;
    float rstd = rsqrtf(var + GEPS);

    // phase 1: one pixel per thread
    {
        int n = n0 + tid;
        const float* q = t2 + ((size_t)b * NN + n) * KCH;
        float sim[NCLS] = {};
        for (int c = 0; c < KCH; c += 4) {
            float4 q4 = *(const float4*)(q + c);
            float qv[4] = {q4.x, q4.y, q4.z, q4.w};
            #pragma unroll
            for (int e = 0; e < 4; e++) {
                float qn = fmaxf((qv[e] - mean) * rstd * sgam[c + e] + sbet[c + e], 0.f);
                #pragma unroll
                for (int k = 0; k < NCLS; k++) sim[k] += qn * sk[(c + e) * NCLS + k];
            }
        }
        const float scale = 0.08838834764831845f;
        float m = -1e30f;
        #pragma unroll
        for (int k = 0; k < NCLS; k++) { sim[k] *= scale; m = fmaxf(m, sim[k]); }
        float ssum = 0.f;
        #pragma unroll
        for (int k = 0; k < NCLS; k++) { sim[k] = __expf(sim[k] - m); ssum += sim[k]; }
        float inv = 1.0f / ssum;
        #pragma unroll
        for (int k = 0; k < NCLS; k++) sims[tid][k] = sim[k] * inv;
    }
    __syncthreads();
    // phase 2: coalesced bf16 NHWC output; 64 lanes cover 128 c as ushort2
    int c2 = (tid & 63) * 2;
    int psub = tid >> 6;
    for (int p = psub; p < 256; p += 4) {
        float a0 = 0.f, a1 = 0.f;
        #pragma unroll
        for (int k = 0; k < NCLS; k++) {
            float pr = sims[p][k];
            a0 += pr * sv[c2 * NCLS + k];
            a1 += pr * sv[(c2 + 1) * NCLS + k];
        }
        ushort2 st; st.x = f2bfu(a0); st.y = f2bfu(a1);
        *(ushort2*)&att[((size_t)b * NN + n0 + p) * KCH + c2] = st;
    }
}

// ---- final: t4 NHWC bf16 -> GN+relu -> d_out NCHW fp32 (tiled transpose) ----
__global__ __launch_bounds__(256) void final_kernel(
    const u16* __restrict__ t4, float* __restrict__ outp,
    const float* __restrict__ stat,
    const float* __restrict__ g, const float* __restrict__ bb)
{
    __shared__ float tile[64][65];
    int b = blockIdx.z, c0 = blockIdx.y * 64, n0 = blockIdx.x * 64;
    int tid = threadIdx.x, tx = tid & 63, ty = tid >> 6;
    const float cinv = 1.0f / (256.f * 16384.f);
    float sm = stat[2 * b], sq = stat[2 * b + 1];
    float mean = sm * cinv;
    float var = sq * cinv - mean * mean;
    float rstd = rsqrtf(var + GEPS);
    #pragma unroll
    for (int r = 0; r < 16; r++) {
        int nl = ty * 16 + r;
        tile[nl][tx] = bfu2f(t4[((size_t)b * NN + n0 + nl) * CC + c0 + tx]);
    }
    __syncthreads();
    #pragma unroll
    for (int r = 0; r < 16; r++) {
        int c = c0 + ty * 16 + r;
        float v = (tile[tx][ty * 16 + r] - mean) * rstd * g[c] + bb[c];
        outp[((size_t)(b * CC + c)) * NN + n0 + tx] = fmaxf(v, 0.f);
    }
}

extern "C" void kernel_launch(void* const* d_in, const int* in_sizes, int n_in,
                              void* d_out, int out_size, void* d_ws, size_t ws_size,
                              hipStream_t stream) {
    const float* feats   = (const float*)d_in[0];
    const float* out_aux = (const float*)d_in[1];
    const float* fp_w1 = (const float*)d_in[2];
    const float* fp_g1 = (const float*)d_in[3];
    const float* fp_b1 = (const float*)d_in[4];
    const float* fp_w2 = (const float*)d_in[5];
    const float* fp_g2 = (const float*)d_in[6];
    const float* fp_b2 = (const float*)d_in[7];
    const float* fo_w1 = (const float*)d_in[8];
    const float* fo_g1 = (const float*)d_in[9];
    const float* fo_b1 = (const float*)d_in[10];
    const float* fo_w2 = (const float*)d_in[11];
    const float* fo_g2 = (const float*)d_in[12];
    const float* fo_b2 = (const float*)d_in[13];
    const float* fd_w  = (const float*)d_in[14];
    const float* fd_g  = (const float*)d_in[15];
    const float* fd_b  = (const float*)d_in[16];
    const float* fu_w  = (const float*)d_in[17];
    const float* fu_g  = (const float*)d_in[18];
    const float* fu_b  = (const float*)d_in[19];
    const float* cb_w  = (const float*)d_in[20];
    const float* cb_g  = (const float*)d_in[21];
    const float* cb_b  = (const float*)d_in[22];

    float* ws = (float*)d_ws;
    float* stats = ws + OFF_STATS;
    float* ctx   = ws + OFF_CTX;
    float* kmat  = ws + OFF_KMAT;
    float* vmat  = ws + OFF_VMAT;
    u16* wb1 = (u16*)(ws + OFF_WB1);
    u16* wb2 = (u16*)(ws + OFF_WB2);
    u16* wb3 = (u16*)(ws + OFF_WB3);
    u16* wb4 = (u16*)(ws + OFF_WB4);
    u16* featsb = (u16*)(ws + OFF_FEATSB);
    float* pool = ws + OFF_POOL;
    float* probs = pool;
    float* t1 = pool;
    u16* x2b = (u16*)(pool + 16777216);
    float* t2 = pool;
    u16* attb = (u16*)(pool + 25165824);
    u16* t3b = (u16*)pool;
    u16* x4ab = (u16*)(pool + 16777216);
    u16* t4b = (u16*)pool;
    float* st0 = stats, *st1 = stats + 16, *st2 = stats + 32, *st3 = stats + 48;

    hipMemsetAsync(stats, 0, 64 * sizeof(float), stream);

    conv_weights<<<832, 256, 0, stream>>>(fp_w1, fp_w2, fu_w, cb_w, wb1, wb2, wb3, wb4);
    feats_to_nhwc<<<dim3(NN / 64, CC / 64, BB), 256, 0, stream>>>(feats, featsb);
    interp_softmax_kernel<<<BB * NCLS, 256, 0, stream>>>(out_aux, probs);
    ctx_kernel<<<dim3(CC, BB), 256, 0, stream>>>(feats, probs, ctx);
    kv_kernel<<<BB, 256, 0, stream>>>(ctx, fo_w1, fo_g1, fo_b1, fo_w2, fo_g2, fo_b2,
                                      fd_w, fd_g, fd_b, kmat, vmat);
    // t1 = feats @ w1^T  [b][n][128] fp32, stats0
    mfma_gemm<256, 256, false><<<dim3(NN / 128, 1, BB), 256, 0, stream>>>(
        featsb, nullptr, wb1, t1, KCH, st0);
    // x2 = relu(gn(t1)) bf16
    norm_convert<false><<<2097152 / 256, 256, 0, stream>>>(
        t1, x2b, st0, 1.f / (KCH * (float)NN), fp_g1, fp_b1, 127, 18);
    // t2 = x2 @ w2^T fp32, stats1
    mfma_gemm<128, 128, false><<<dim3(NN / 128, 1, BB), 256, 0, stream>>>(
        x2b, nullptr, wb2, t2, KCH, st1);
    // att bf16 NHWC
    attn_kernel<<<dim3(NN / 256, BB), 256, 0, stream>>>(
        t2, kmat, vmat, st1, fp_g2, fp_b2, attb);
    // t3 = att @ fu_w^T bf16, stats2
    mfma_gemm<128, 128, true><<<dim3(NN / 128, 2, BB), 256, 0, stream>>>(
        attb, nullptr, wb3, t3b, CC, st2);
    // x4a = relu(gn(t3)) bf16
    norm_convert<true><<<4194304 / 256, 256, 0, stream>>>(
        t3b, x4ab, st2, 1.f / (CC * (float)NN), fu_g, fu_b, 255, 19);
    // t4 = concat(x4a, featsb) @ cb_w^T bf16, stats3
    mfma_gemm<512, 256, true><<<dim3(NN / 128, 2, BB), 256, 0, stream>>>(
        x4ab, featsb, wb4, t4b, CC, st3);
    // final GN+relu+transpose to NCHW fp32
    final_kernel<<<dim3(NN / 64, CC / 64, BB), 256, 0, stream>>>(
        t4b, (float*)d_out, st3, cb_g, cb_b);
}

// Round 4
// 791.163 us; speedup vs baseline: 3.1089x; 1.1573x over previous
//
#include <hip/hip_runtime.h>
#include <hip/hip_bf16.h>

#define BB 8
#define CC 256
#define KCH 128
#define NCLS 21
#define NN 16384          // 128*128
#define IH 64
#define IW 64
#define GEPS 1e-5f

typedef unsigned short u16;
typedef short v8s __attribute__((ext_vector_type(8)));
typedef u16 v8us __attribute__((ext_vector_type(8)));
typedef float v4f __attribute__((ext_vector_type(4)));

// ---- workspace layout (float elements) ----
#define OFF_STATS   0u          // 128: st0..st3 @0/16/32/48, stK1@64, stV@80, stK2@96
#define OFF_CTX     128u        // 43008 -> 43136
#define OFF_KMAT    43136u      // 21504 -> 64640   (h2raw)
#define OFF_VMAT    64640u      // 21504 -> 86144   (v1raw)
#define OFF_WB1     86144u      // 16384 -> 102528
#define OFF_WB2     102528u     // 8192  -> 110720
#define OFF_WB3     110720u     // 16384 -> 127104
#define OFF_WB4     127104u     // 65536 -> 192640
#define OFF_FEATSB  196608u     // 16777216 -> 16973824
#define OFF_POOL    16973824u
// pool timeline (stream-ordered):
//   probs fp32 2752512 @POOL+0 (interp->ctx)
//   h1raw fp32 21504   @POOL+0 (kv1->kv2; probs dead)
//   t1    fp32 16777216 @POOL+0
//   x2    bf16 @POOL+16777216
//   t2    fp32 @POOL+0
//   att   bf16 @POOL+25165824
//   t3    bf16 @POOL+0
//   x4a   bf16 @POOL+16777216
//   t4    bf16 @POOL+0
// peak end = POOL + 33554432 = 50528256 floats (proven fit in R1)

__device__ __forceinline__ float bfu2f(u16 u) {
    unsigned int x = ((unsigned int)u) << 16;
    return __uint_as_float(x);
}
__device__ __forceinline__ u16 f2bfu(float f) {
    __hip_bfloat16 h = __float2bfloat16(f);
    return *reinterpret_cast<u16*>(&h);
}

__device__ __forceinline__ float blk_sum(float v, float* red) {
    #pragma unroll
    for (int o = 32; o > 0; o >>= 1) v += __shfl_down(v, o, 64);
    int lane = threadIdx.x & 63, w = threadIdx.x >> 6;
    __syncthreads();
    if (lane == 0) red[w] = v;
    __syncthreads();
    return red[0] + red[1] + red[2] + red[3];
}
__device__ __forceinline__ float blk_max(float v, float* red) {
    #pragma unroll
    for (int o = 32; o > 0; o >>= 1) v = fmaxf(v, __shfl_down(v, o, 64));
    int lane = threadIdx.x & 63, w = threadIdx.x >> 6;
    __syncthreads();
    if (lane == 0) red[w] = v;
    __syncthreads();
    return fmaxf(fmaxf(red[0], red[1]), fmaxf(red[2], red[3]));
}

// dual (sum,sumsq) block reduce + one atomic pair
__device__ __forceinline__ void stat_atomic(float s, float s2, float* target) {
    __shared__ float r2[8];
    #pragma unroll
    for (int o = 32; o > 0; o >>= 1) {
        s += __shfl_down(s, o, 64);
        s2 += __shfl_down(s2, o, 64);
    }
    int lane = threadIdx.x & 63, w = threadIdx.x >> 6;
    if (lane == 0) { r2[w] = s; r2[4 + w] = s2; }
    __syncthreads();
    if (threadIdx.x == 0) {
        atomicAdd(&target[0], r2[0] + r2[1] + r2[2] + r2[3]);
        atomicAdd(&target[1], r2[4] + r2[5] + r2[6] + r2[7]);
    }
}

// ---- weights fp32 -> bf16 ----
__global__ __launch_bounds__(256) void conv_weights(
    const float* __restrict__ w1, const float* __restrict__ w2,
    const float* __restrict__ w3, const float* __restrict__ w4,
    u16* __restrict__ o1, u16* __restrict__ o2,
    u16* __restrict__ o3, u16* __restrict__ o4)
{
    int i = blockIdx.x * 256 + threadIdx.x;
    if (i < 32768) o1[i] = f2bfu(w1[i]);
    else if (i < 49152) o2[i - 32768] = f2bfu(w2[i - 32768]);
    else if (i < 81920) o3[i - 49152] = f2bfu(w3[i - 49152]);
    else if (i < 212992) o4[i - 81920] = f2bfu(w4[i - 81920]);
}

// ---- feats NCHW fp32 -> NHWC bf16 (tiled transpose) ----
__global__ __launch_bounds__(256) void feats_to_nhwc(
    const float* __restrict__ feats, u16* __restrict__ outp)
{
    __shared__ float tile[64][65];
    int b = blockIdx.z, c0 = blockIdx.y * 64, n0 = blockIdx.x * 64;
    int tid = threadIdx.x, tx = tid & 63, ty = tid >> 6;
    #pragma unroll
    for (int r = 0; r < 16; r++) {
        int c = ty * 16 + r;
        tile[c][tx] = feats[((size_t)(b * CC + c0 + c)) * NN + n0 + tx];
    }
    __syncthreads();
    #pragma unroll
    for (int r = 0; r < 16; r++) {
        int nl = ty * 16 + r;
        outp[((size_t)b * NN + n0 + nl) * CC + c0 + tx] = f2bfu(tile[tx][nl]);
    }
}

// ---- K1: bilinear (align_corners) 64x64 -> 128x128 + spatial softmax ----
__global__ __launch_bounds__(256) void interp_softmax_kernel(
    const float* __restrict__ aux, float* __restrict__ probs)
{
    int bk = blockIdx.x;                 // b*21 + k
    const float* src = aux + (size_t)bk * (IH * IW);
    float* dst = probs + (size_t)bk * NN;
    int tid = threadIdx.x;
    __shared__ float red[4];
    const float scale = 63.0f / 127.0f;
    float lmax = -1e30f;
    for (int idx = tid; idx < NN; idx += 256) {
        int y = idx >> 7, x = idx & 127;
        float fy = y * scale, fx = x * scale;
        int y0 = (int)fy, x0 = (int)fx;
        float wy = fy - y0, wx = fx - x0;
        int y1 = min(y0 + 1, IH - 1), x1 = min(x0 + 1, IW - 1);
        float v00 = src[y0 * IW + x0];
        float v01 = src[y0 * IW + x1];
        float v10 = src[y1 * IW + x0];
        float v11 = src[y1 * IW + x1];
        float v = (v00 * (1.f - wx) + v01 * wx) * (1.f - wy)
                + (v10 * (1.f - wx) + v11 * wx) * wy;
        dst[idx] = v;
        lmax = fmaxf(lmax, v);
    }
    float gmax = blk_max(lmax, red);
    float lsum = 0.f;
    for (int idx = tid; idx < NN; idx += 256) {
        float e = __expf(dst[idx] - gmax);
        dst[idx] = e;
        lsum += e;
    }
    float gsum = blk_sum(lsum, red);
    float inv = 1.0f / gsum;
    for (int idx = tid; idx < NN; idx += 256) dst[idx] *= inv;
}

// ---- K2: ctx[b,c,k] = sum_n probs[b,k,n] * feats[b,c,n] (NCHW feats) ----
__global__ __launch_bounds__(256) void ctx_kernel(
    const float* __restrict__ feats, const float* __restrict__ probs,
    float* __restrict__ ctx)
{
    int c = blockIdx.x, b = blockIdx.y, tid = threadIdx.x;
    const float* f = feats + ((size_t)(b * CC + c)) * NN;
    const float* p = probs + (size_t)b * NCLS * NN;
    float acc[NCLS];
    #pragma unroll
    for (int k = 0; k < NCLS; k++) acc[k] = 0.f;
    for (int n = tid; n < NN; n += 256) {
        float fv = f[n];
        #pragma unroll
        for (int k = 0; k < NCLS; k++) acc[k] += fv * p[(size_t)k * NN + n];
    }
    __shared__ float red[4 * NCLS];
    int lane = tid & 63, w = tid >> 6;
    #pragma unroll
    for (int k = 0; k < NCLS; k++) {
        float v = acc[k];
        #pragma unroll
        for (int o = 32; o > 0; o >>= 1) v += __shfl_down(v, o, 64);
        if (lane == 0) red[w * NCLS + k] = v;
    }
    __syncthreads();
    if (tid < NCLS) {
        ctx[((size_t)(b * CC + c)) * NCLS + tid] =
            red[tid] + red[NCLS + tid] + red[2 * NCLS + tid] + red[3 * NCLS + tid];
    }
}

// ---- kv1: h1raw = fo_w1 @ ctx (branch 0), v1raw = fd_w @ ctx (branch 1) ----
// grid (11, 2, 8); one thread per output element; ctx[b] staged in LDS.
__global__ __launch_bounds__(256) void kv1_kernel(
    const float* __restrict__ ctx, const float* __restrict__ fo_w1,
    const float* __restrict__ fd_w,
    float* __restrict__ h1raw, float* __restrict__ v1raw,
    float* __restrict__ kvstat)   // [branch][8b][2]
{
    __shared__ float sctx[CC * NCLS];
    int b = blockIdx.z, br = blockIdx.y, tid = threadIdx.x;
    for (int i = tid; i < CC * NCLS; i += 256)
        sctx[i] = ctx[(size_t)b * CC * NCLS + i];
    __syncthreads();
    int idx = blockIdx.x * 256 + tid;
    const float* W = br ? fd_w : fo_w1;
    float* dst = br ? v1raw : h1raw;
    float s = 0.f, s2 = 0.f;
    if (idx < KCH * NCLS) {
        int o = idx / NCLS, k = idx - o * NCLS;
        const float* w = W + (size_t)o * CC;
        float acc = 0.f;
        #pragma unroll 4
        for (int c = 0; c < CC; c++) acc += w[c] * sctx[c * NCLS + k];
        dst[(size_t)b * KCH * NCLS + idx] = acc;
        s = acc; s2 = acc * acc;
    }
    stat_atomic(s, s2, &kvstat[(br * 8 + b) * 2]);
}

// ---- kv2: h2raw = fo_w2 @ relu(gn(h1raw)); grid (11, 1, 8) ----
__global__ __launch_bounds__(256) void kv2_kernel(
    const float* __restrict__ h1raw, const float* __restrict__ fo_w2,
    const float* __restrict__ g1, const float* __restrict__ b1,
    const float* __restrict__ st_in, float* __restrict__ h2raw,
    float* __restrict__ st_out)
{
    __shared__ float sh[KCH * NCLS];
    int b = blockIdx.z, tid = threadIdx.x;
    const float ninv = 1.0f / (KCH * NCLS);
    float sm = st_in[b * 2], sq = st_in[b * 2 + 1];
    float mean = sm * ninv;
    float var = sq * ninv - mean * mean;
    float rstd = rsqrtf(var + GEPS);
    for (int i = tid; i < KCH * NCLS; i += 256) {
        int c = i / NCLS;
        float v = (h1raw[(size_t)b * KCH * NCLS + i] - mean) * rstd * g1[c] + b1[c];
        sh[i] = fmaxf(v, 0.f);
    }
    __syncthreads();
    int idx = blockIdx.x * 256 + tid;
    float s = 0.f, s2 = 0.f;
    if (idx < KCH * NCLS) {
        int o = idx / NCLS, k = idx - o * NCLS;
        const float* w = fo_w2 + (size_t)o * KCH;
        float acc = 0.f;
        #pragma unroll 4
        for (int c = 0; c < KCH; c++) acc += w[c] * sh[c * NCLS + k];
        h2raw[(size_t)b * KCH * NCLS + idx] = acc;
        s = acc; s2 = acc * acc;
    }
    stat_atomic(s, s2, &st_out[b * 2]);
}

// ---- MFMA GEMM: out[b][n][o] = sum_c X[b][n][c] * W[o][c]  (all bf16 in) ----
template<int KTOT, int K1, bool OUT_BF16>
__global__ __launch_bounds__(256) void mfma_gemm(
    const u16* __restrict__ xa, const u16* __restrict__ xb,
    const u16* __restrict__ wmat, void* __restrict__ outv,
    int Odim, float* __restrict__ ostat)
{
    __shared__ u16 lA[128 * 32];
    __shared__ u16 lB[128 * 32];
    __shared__ float red[8];
    const int b = blockIdx.z;
    const int n0 = blockIdx.x * 128;
    const int o0 = blockIdx.y * 128;
    const int tid = threadIdx.x;
    const int wave = tid >> 6, lane = tid & 63;
    const int quad = lane >> 4, l15 = lane & 15;
    const int wm = (wave & 1) * 64, wn = (wave >> 1) * 64;
    const int srow = lane >> 2;
    const int skc = (lane & 3) * 8;
    const size_t xbase = (size_t)b * NN + n0;

    v4f acc[4][4] = {};

    for (int c0 = 0; c0 < KTOT; c0 += 32) {
        #pragma unroll
        for (int t = 0; t < 2; t++) {
            int inst = wave * 2 + t;
            int row = inst * 16 + srow;
            int cc = c0 + skc;
            const u16* src;
            if (K1 == KTOT || cc < K1)
                src = xa + (xbase + row) * K1 + cc;
            else
                src = xb + (xbase + row) * (KTOT - K1) + (cc - K1);
            v8s v = *(const v8s*)src;
            *(v8s*)&lA[inst * 512 + lane * 8] = v;
        }
        #pragma unroll
        for (int t = 0; t < 2; t++) {
            int inst = wave * 2 + t;
            int row = inst * 16 + srow;
            v8s v = *(const v8s*)(wmat + (size_t)(o0 + row) * KTOT + c0 + skc);
            *(v8s*)&lB[inst * 512 + lane * 8] = v;
        }
        __syncthreads();
        v8s af[4], bfr[4];
        #pragma unroll
        for (int i = 0; i < 4; i++)
            af[i] = *(const v8s*)&lA[(wm + i * 16 + l15) * 32 + quad * 8];
        #pragma unroll
        for (int j = 0; j < 4; j++)
            bfr[j] = *(const v8s*)&lB[(wn + j * 16 + l15) * 32 + quad * 8];
        #pragma unroll
        for (int i = 0; i < 4; i++)
            #pragma unroll
            for (int j = 0; j < 4; j++)
                acc[i][j] = __builtin_amdgcn_mfma_f32_16x16x32_bf16(
                    af[i], bfr[j], acc[i][j], 0, 0, 0);
        __syncthreads();
    }

    float s = 0.f, s2 = 0.f;
    #pragma unroll
    for (int i = 0; i < 4; i++) {
        #pragma unroll
        for (int j = 0; j < 4; j++) {
            #pragma unroll
            for (int r = 0; r < 4; r++) {
                float v = acc[i][j][r];
                int n = n0 + wm + i * 16 + quad * 4 + r;
                int o = o0 + wn + j * 16 + l15;
                size_t addr = ((size_t)b * NN + n) * (size_t)Odim + o;
                if (OUT_BF16) ((u16*)outv)[addr] = f2bfu(v);
                else ((float*)outv)[addr] = v;
                s += v; s2 += v * v;
            }
        }
    }
    #pragma unroll
    for (int o = 32; o > 0; o >>= 1) {
        s += __shfl_down(s, o, 64);
        s2 += __shfl_down(s2, o, 64);
    }
    if (lane == 0) { red[wave] = s; red[4 + wave] = s2; }
    __syncthreads();
    if (tid == 0) {
        atomicAdd(&ostat[2 * b], red[0] + red[1] + red[2] + red[3]);
        atomicAdd(&ostat[2 * b + 1], red[4] + red[5] + red[6] + red[7]);
    }
}

// ---- GN+relu+bf16 convert, NHWC elementwise, 8 elems/thread ----
template<bool IN_BF16>
__global__ __launch_bounds__(256) void norm_convert(
    const void* __restrict__ inv, u16* __restrict__ outp,
    const float* __restrict__ stat, float ninv,
    const float* __restrict__ gam, const float* __restrict__ bet,
    int cmask, int bshift8)
{
    size_t f8 = (size_t)blockIdx.x * 256 + threadIdx.x;
    int b = (int)(f8 >> bshift8);
    int c = (int)((f8 * 8) & (size_t)cmask);
    float sm = stat[2 * b], sq = stat[2 * b + 1];
    float mean = sm * ninv;
    float var = sq * ninv - mean * mean;
    float rstd = rsqrtf(var + GEPS);
    float x[8];
    if (IN_BF16) {
        v8us v = ((const v8us*)inv)[f8];
        #pragma unroll
        for (int e = 0; e < 8; e++) x[e] = bfu2f(v[e]);
    } else {
        const float4* p = (const float4*)inv + f8 * 2;
        float4 a = p[0], d = p[1];
        x[0] = a.x; x[1] = a.y; x[2] = a.z; x[3] = a.w;
        x[4] = d.x; x[5] = d.y; x[6] = d.z; x[7] = d.w;
    }
    v8us o;
    #pragma unroll
    for (int e = 0; e < 8; e++) {
        float v = (x[e] - mean) * rstd * gam[c + e] + bet[c + e];
        o[e] = f2bfu(fmaxf(v, 0.f));
    }
    ((v8us*)outp)[f8] = o;
}

// ---- attention: q=relu(gn(t2)); k/v normalized on load; att bf16 NHWC ----
__global__ __launch_bounds__(256) void attn_kernel(
    const float* __restrict__ t2, const float* __restrict__ kraw,
    const float* __restrict__ vraw, const float* __restrict__ stat,
    const float* __restrict__ g2, const float* __restrict__ b2,
    const float* __restrict__ stK, const float* __restrict__ ko_g,
    const float* __restrict__ ko_b,
    const float* __restrict__ stV, const float* __restrict__ vd_g,
    const float* __restrict__ vd_b,
    u16* __restrict__ att)
{
    __shared__ float sk[KCH * NCLS];
    __shared__ float sv[KCH * NCLS];
    __shared__ float sgam[KCH], sbet[KCH];
    __shared__ float sims[256][NCLS + 1];
    int b = blockIdx.y;
    int n0 = blockIdx.x * 256;
    int tid = threadIdx.x;
    const float kvinv = 1.0f / (KCH * NCLS);
    float km = stK[b * 2] * kvinv;
    float kv2_ = stK[b * 2 + 1] * kvinv;
    float krs = rsqrtf(kv2_ - km * km + GEPS);
    float vm = stV[b * 2] * kvinv;
    float vv2 = stV[b * 2 + 1] * kvinv;
    float vrs = rsqrtf(vv2 - vm * vm + GEPS);
    for (int i = tid; i < KCH * NCLS; i += 256) {
        int c = i / NCLS;
        size_t base = (size_t)b * KCH * NCLS + i;
        sk[i] = fmaxf((kraw[base] - km) * krs * ko_g[c] + ko_b[c], 0.f);
        sv[i] = fmaxf((vraw[base] - vm) * vrs * vd_g[c] + vd_b[c], 0.f);
    }
    if (tid < KCH) { sgam[tid] = g2[tid]; sbet[tid] = b2[tid]; }
    __syncthreads();
    const float cinv = 1.0f / (128.f * 16384.f);
    float sm = stat[2 * b], sq = stat[2 * b + 1];
    float mean = sm * cinv;
    float var = sq * cinv - mean * mean;
    float rstd = rsqrtf(var + GEPS);

    {
        int n = n0 + tid;
        const float* q = t2 + ((size_t)b * NN + n) * KCH;
        float sim[NCLS] = {};
        for (int c = 0; c < KCH; c += 4) {
            float4 q4 = *(const float4*)(q + c);
            float qv[4] = {q4.x, q4.y, q4.z, q4.w};
            #pragma unroll
            for (int e = 0; e < 4; e++) {
                float qn = fmaxf((qv[e] - mean) * rstd * sgam[c + e] + sbet[c + e], 0.f);
                #pragma unroll
                for (int k = 0; k < NCLS; k++) sim[k] += qn * sk[(c + e) * NCLS + k];
            }
        }
        const float scale = 0.08838834764831845f;
        float m = -1e30f;
        #pragma unroll
        for (int k = 0; k < NCLS; k++) { sim[k] *= scale; m = fmaxf(m, sim[k]); }
        float ssum = 0.f;
        #pragma unroll
        for (int k = 0; k < NCLS; k++) { sim[k] = __expf(sim[k] - m); ssum += sim[k]; }
        float inv = 1.0f / ssum;
        #pragma unroll
        for (int k = 0; k < NCLS; k++) sims[tid][k] = sim[k] * inv;
    }
    __syncthreads();
    int c2 = (tid & 63) * 2;
    int psub = tid >> 6;
    for (int p = psub; p < 256; p += 4) {
        float a0 = 0.f, a1 = 0.f;
        #pragma unroll
        for (int k = 0; k < NCLS; k++) {
            float pr = sims[p][k];
            a0 += pr * sv[c2 * NCLS + k];
            a1 += pr * sv[(c2 + 1) * NCLS + k];
        }
        ushort2 st; st.x = f2bfu(a0); st.y = f2bfu(a1);
        *(ushort2*)&att[((size_t)b * NN + n0 + p) * KCH + c2] = st;
    }
}

// ---- final: t4 NHWC bf16 -> GN+relu -> d_out NCHW fp32 ----
__global__ __launch_bounds__(256) void final_kernel(
    const u16* __restrict__ t4, float* __restrict__ outp,
    const float* __restrict__ stat,
    const float* __restrict__ g, const float* __restrict__ bb)
{
    __shared__ float tile[64][65];
    int b = blockIdx.z, c0 = blockIdx.y * 64, n0 = blockIdx.x * 64;
    int tid = threadIdx.x, tx = tid & 63, ty = tid >> 6;
    const float cinv = 1.0f / (256.f * 16384.f);
    float sm = stat[2 * b], sq = stat[2 * b + 1];
    float mean = sm * cinv;
    float var = sq * cinv - mean * mean;
    float rstd = rsqrtf(var + GEPS);
    #pragma unroll
    for (int r = 0; r < 16; r++) {
        int nl = ty * 16 + r;
        tile[nl][tx] = bfu2f(t4[((size_t)b * NN + n0 + nl) * CC + c0 + tx]);
    }
    __syncthreads();
    #pragma unroll
    for (int r = 0; r < 16; r++) {
        int c = c0 + ty * 16 + r;
        float v = (tile[tx][ty * 16 + r] - mean) * rstd * g[c] + bb[c];
        outp[((size_t)(b * CC + c)) * NN + n0 + tx] = fmaxf(v, 0.f);
    }
}

extern "C" void kernel_launch(void* const* d_in, const int* in_sizes, int n_in,
                              void* d_out, int out_size, void* d_ws, size_t ws_size,
                              hipStream_t stream) {
    const float* feats   = (const float*)d_in[0];
    const float* out_aux = (const float*)d_in[1];
    const float* fp_w1 = (const float*)d_in[2];
    const float* fp_g1 = (const float*)d_in[3];
    const float* fp_b1 = (const float*)d_in[4];
    const float* fp_w2 = (const float*)d_in[5];
    const float* fp_g2 = (const float*)d_in[6];
    const float* fp_b2 = (const float*)d_in[7];
    const float* fo_w1 = (const float*)d_in[8];
    const float* fo_g1 = (const float*)d_in[9];
    const float* fo_b1 = (const float*)d_in[10];
    const float* fo_w2 = (const float*)d_in[11];
    const float* fo_g2 = (const float*)d_in[12];
    const float* fo_b2 = (const float*)d_in[13];
    const float* fd_w  = (const float*)d_in[14];
    const float* fd_g  = (const float*)d_in[15];
    const float* fd_b  = (const float*)d_in[16];
    const float* fu_w  = (const float*)d_in[17];
    const float* fu_g  = (const float*)d_in[18];
    const float* fu_b  = (const float*)d_in[19];
    const float* cb_w  = (const float*)d_in[20];
    const float* cb_g  = (const float*)d_in[21];
    const float* cb_b  = (const float*)d_in[22];

    float* ws = (float*)d_ws;
    float* stats = ws + OFF_STATS;
    float* ctx   = ws + OFF_CTX;
    float* kmat  = ws + OFF_KMAT;   // h2raw
    float* vmat  = ws + OFF_VMAT;   // v1raw
    u16* wb1 = (u16*)(ws + OFF_WB1);
    u16* wb2 = (u16*)(ws + OFF_WB2);
    u16* wb3 = (u16*)(ws + OFF_WB3);
    u16* wb4 = (u16*)(ws + OFF_WB4);
    u16* featsb = (u16*)(ws + OFF_FEATSB);
    float* pool = ws + OFF_POOL;
    float* probs = pool;
    float* h1raw = pool;            // probs dead after ctx_kernel
    float* t1 = pool;
    u16* x2b = (u16*)(pool + 16777216);
    float* t2 = pool;
    u16* attb = (u16*)(pool + 25165824);
    u16* t3b = (u16*)pool;
    u16* x4ab = (u16*)(pool + 16777216);
    u16* t4b = (u16*)pool;
    float* st0 = stats, *st1 = stats + 16, *st2 = stats + 32, *st3 = stats + 48;
    float* stK1 = stats + 64, *stV = stats + 80, *stK2 = stats + 96;

    hipMemsetAsync(stats, 0, 128 * sizeof(float), stream);

    conv_weights<<<832, 256, 0, stream>>>(fp_w1, fp_w2, fu_w, cb_w, wb1, wb2, wb3, wb4);
    feats_to_nhwc<<<dim3(NN / 64, CC / 64, BB), 256, 0, stream>>>(feats, featsb);
    interp_softmax_kernel<<<BB * NCLS, 256, 0, stream>>>(out_aux, probs);
    ctx_kernel<<<dim3(CC, BB), 256, 0, stream>>>(feats, probs, ctx);
    // kv pipeline (parallelized): kv1 -> kv2; final normalize fused into attn
    kv1_kernel<<<dim3(11, 2, BB), 256, 0, stream>>>(
        ctx, fo_w1, fd_w, h1raw, vmat, stK1);     // stK1[0..15]=fo1, [16..31]=fd -> stV
    kv2_kernel<<<dim3(11, 1, BB), 256, 0, stream>>>(
        h1raw, fo_w2, fo_g1, fo_b1, stK1, kmat, stK2);
    // t1 = feats @ w1^T  [b][n][128] fp32, stats0
    mfma_gemm<256, 256, false><<<dim3(NN / 128, 1, BB), 256, 0, stream>>>(
        featsb, nullptr, wb1, t1, KCH, st0);
    // x2 = relu(gn(t1)) bf16
    norm_convert<false><<<2097152 / 256, 256, 0, stream>>>(
        t1, x2b, st0, 1.f / (KCH * (float)NN), fp_g1, fp_b1, 127, 18);
    // t2 = x2 @ w2^T fp32, stats1
    mfma_gemm<128, 128, false><<<dim3(NN / 128, 1, BB), 256, 0, stream>>>(
        x2b, nullptr, wb2, t2, KCH, st1);
    // att bf16 NHWC (k/v normalized on load)
    attn_kernel<<<dim3(NN / 256, BB), 256, 0, stream>>>(
        t2, kmat, vmat, st1, fp_g2, fp_b2,
        stK2, fo_g2, fo_b2, stV, fd_g, fd_b, attb);
    // t3 = att @ fu_w^T bf16, stats2
    mfma_gemm<128, 128, true><<<dim3(NN / 128, 2, BB), 256, 0, stream>>>(
        attb, nullptr, wb3, t3b, CC, st2);
    // x4a = relu(gn(t3)) bf16
    norm_convert<true><<<4194304 / 256, 256, 0, stream>>>(
        t3b, x4ab, st2, 1.f / (CC * (float)NN), fu_g, fu_b, 255, 19);
    // t4 = concat(x4a, featsb) @ cb_w^T bf16, stats3
    mfma_gemm<512, 256, true><<<dim3(NN / 128, 2, BB), 256, 0, stream>>>(
        x4ab, featsb, wb4, t4b, CC, st3);
    // final GN+relu+transpose to NCHW fp32
    final_kernel<<<dim3(NN / 64, CC / 64, BB), 256, 0, stream>>>(
        t4b, (float*)d_out, st3, cb_g, cb_b);
}